// Round 1
// baseline (1491.240 us; speedup 1.0000x reference)
//
#include <hip/hip_runtime.h>
#include <math.h>

#define NB 1024
#define NT 64
#define NH 512
#define NE 200000
#define NG (3 * NH)
#define MALL (NB * NT)
#define LN_EPS 1e-5f

typedef __bf16 bf16;
typedef __attribute__((ext_vector_type(8))) __bf16 bf16x8;
typedef __attribute__((ext_vector_type(4))) float f32x4;

// ---------------- LayerNorm block statistics (256 threads, 512 elems) -------
__device__ __forceinline__ void ln_stats(float sum, float sq, float& mean, float& rstd) {
#pragma unroll
  for (int o = 32; o > 0; o >>= 1) {
    sum += __shfl_down(sum, o);
    sq  += __shfl_down(sq, o);
  }
  __shared__ float red[8];
  const int wid = threadIdx.x >> 6;
  if ((threadIdx.x & 63) == 0) { red[wid * 2] = sum; red[wid * 2 + 1] = sq; }
  __syncthreads();
  if (threadIdx.x == 0) {
    const float ts = red[0] + red[2] + red[4] + red[6];
    const float tq = red[1] + red[3] + red[5] + red[7];
    const float m  = ts * (1.0f / NH);
    const float var = tq * (1.0f / NH) - m * m;
    red[0] = m;
    red[1] = rsqrtf(var + LN_EPS);
  }
  __syncthreads();
  mean = red[0];
  rstd = red[1];
}

__device__ __forceinline__ float sigmoid_f(float x) {
  return 1.0f / (1.0f + __expf(-x));
}
__device__ __forceinline__ float tanh_f(float x) {
  x = fminf(fmaxf(x, -15.0f), 15.0f);
  const float e = __expf(2.0f * x);
  return (e - 1.0f) / (e + 1.0f);
}

// ---------------- active mask ----------------------------------------------
__global__ void active_kernel(const int* __restrict__ actions,
                              const int* __restrict__ stopidx,
                              int* __restrict__ act_mask) {
  const int b = blockIdx.x * blockDim.x + threadIdx.x;
  if (b >= NB) return;
  const int si = stopidx[b];
  bool done = false;
  for (int t = 0; t < NT; ++t) {
    const int a = actions[b * NT + t];
    const bool is_stop = (a == si) || (a < 0);
    act_mask[b * NT + t] = (!done && !is_stop) ? 1 : 0;
    done = done || is_stop;
  }
}

// ---------------- weights fp32 -> bf16 --------------------------------------
__global__ void wcvt_kernel(const float* __restrict__ wih,
                            const float* __restrict__ whh,
                            bf16* __restrict__ wihb, bf16* __restrict__ whhb) {
  const int i = (blockIdx.x * 256 + threadIdx.x) * 4;  // 786432 elems each
  const float4 a = *(const float4*)&wih[i];
  const float4 b = *(const float4*)&whh[i];
  union { bf16 h[4]; uint2 u; } pa, pb;
  pa.h[0] = (bf16)a.x; pa.h[1] = (bf16)a.y; pa.h[2] = (bf16)a.z; pa.h[3] = (bf16)a.w;
  pb.h[0] = (bf16)b.x; pb.h[1] = (bf16)b.y; pb.h[2] = (bf16)b.z; pb.h[3] = (bf16)b.w;
  *(uint2*)&wihb[i] = pa.u;
  *(uint2*)&whhb[i] = pb.u;
}

// ---------------- gather all edge rows -> bf16 X[b*NT+t][H] -----------------
__global__ void xall_kernel(const int* __restrict__ actions,
                            const float* __restrict__ edges,
                            bf16* __restrict__ xbf) {
  const int row = blockIdx.x;  // b*NT + t
  int a = actions[row];
  a = min(max(a, 0), NE - 1);
  const int i = threadIdx.x * 2;
  const float2 v = *(const float2*)&edges[(size_t)a * NH + i];
  union { bf16 h[2]; unsigned u; } p;
  p.h[0] = (bf16)v.x; p.h[1] = (bf16)v.y;
  *(unsigned*)&xbf[(size_t)row * NH + i] = p.u;
}

// ---------------- h0 = LN(question + segment_mean(node_tokens)) -------------
__global__ void h0_kernel(const float* __restrict__ q,
                          const float* __restrict__ nodes,
                          const int* __restrict__ locals,
                          const int* __restrict__ ptr,
                          const float* __restrict__ lnw,
                          const float* __restrict__ lnb,
                          float* __restrict__ h0, bf16* __restrict__ h0b) {
  const int b = blockIdx.x;
  const int i = threadIdx.x * 2;
  const int p0 = ptr[b], p1 = ptr[b + 1];
  const float denom = fmaxf((float)(p1 - p0), 1.0f);
  float s0 = 0.f, s1 = 0.f;
  for (int p = p0; p < p1; ++p) {
    const int node = locals[p];
    const float2 nv = *(const float2*)&nodes[(size_t)node * NH + i];
    s0 += nv.x; s1 += nv.y;
  }
  const float2 qv = *(const float2*)&q[(size_t)b * NH + i];
  const float v0 = qv.x + s0 / denom;
  const float v1 = qv.y + s1 / denom;
  float mean, rstd;
  ln_stats(v0 + v1, v0 * v0 + v1 * v1, mean, rstd);
  const float2 lw = *(const float2*)&lnw[i];
  const float2 lb = *(const float2*)&lnb[i];
  float2 o;
  o.x = (v0 - mean) * rstd * lw.x + lb.x;
  o.y = (v1 - mean) * rstd * lw.y + lb.y;
  *(float2*)&h0[(size_t)b * NH + i] = o;
  union { bf16 h[2]; unsigned u; } p;
  p.h[0] = (bf16)o.x; p.h[1] = (bf16)o.y;
  *(unsigned*)&h0b[(size_t)b * NH + i] = p.u;
}

// ---------------- GI = X @ Wih^T : one big GEMM, hoisted out of the chain ---
// M = B*T = 65536, N = 3H = 1536, K = 512. A,B bf16 (both K-contiguous), C fp32.
// Block: 512 thr (8 waves, 2m x 4n), tile 128x128, BK=64. Per wave 64x32 =
// 4 m-frags x 2 n-frags of 16x16. Grid (12, 512).
#define GI_BK 64
__global__ __launch_bounds__(512) void gi_kernel(const bf16* __restrict__ xbf,
                                                 const bf16* __restrict__ wihb,
                                                 float* __restrict__ gi) {
  __shared__ bf16 As[128][GI_BK + 8];
  __shared__ bf16 Bs[128][GI_BK + 8];
  const int tid = threadIdx.x;
  const int n0 = blockIdx.x * 128;
  const size_t m0 = (size_t)blockIdx.y * 128;
  const int wave = tid >> 6, lane = tid & 63;
  const int ln15 = lane & 15, q8 = (lane >> 4) * 8;
  const int wm = wave >> 2;  // 0..1 -> 64-row half
  const int wn = wave & 3;   // 0..3 -> 32-col tile

  f32x4 acc[4][2] = {};

  for (int kb = 0; kb < NH; kb += GI_BK) {
    if (kb) __syncthreads();
#pragma unroll
    for (int i = 0; i < 2; ++i) {  // 1024 int4-chunks per tile
      const int idx = tid + 512 * i;
      const int row = idx >> 3, c8 = (idx & 7) * 8;
      *(int4*)&As[row][c8] = *(const int4*)&xbf[(m0 + row) * NH + kb + c8];
      *(int4*)&Bs[row][c8] = *(const int4*)&wihb[(size_t)(n0 + row) * NH + kb + c8];
    }
    __syncthreads();
#pragma unroll
    for (int k = 0; k < GI_BK; k += 32) {
      bf16x8 a[4], b[2];
#pragma unroll
      for (int mf = 0; mf < 4; ++mf)
        a[mf] = *(const bf16x8*)&As[wm * 64 + mf * 16 + ln15][k + q8];
#pragma unroll
      for (int nf = 0; nf < 2; ++nf)
        b[nf] = *(const bf16x8*)&Bs[wn * 32 + nf * 16 + ln15][k + q8];
#pragma unroll
      for (int mf = 0; mf < 4; ++mf)
#pragma unroll
        for (int nf = 0; nf < 2; ++nf)
          acc[mf][nf] =
              __builtin_amdgcn_mfma_f32_16x16x32_bf16(a[mf], b[nf], acc[mf][nf], 0, 0, 0);
    }
  }

  const int q4 = (lane >> 4) * 4;
#pragma unroll
  for (int mf = 0; mf < 4; ++mf)
#pragma unroll
    for (int i = 0; i < 4; ++i) {
      const size_t m = m0 + wm * 64 + mf * 16 + q4 + i;
#pragma unroll
      for (int nf = 0; nf < 2; ++nf)
        gi[m * NG + n0 + wn * 32 + nf * 16 + ln15] = acc[mf][nf][i];
    }
}

// ---------------- per-step: GH = h @ Whh^T + fused gate epilogue ------------
// Block: 512 thr = 8 waves. Tile: 64 rows (b) x 32 cols (h). Grid (16,16)=256.
// Only the h-side matmul remains in the serial chain; gi read from GI.
#define BK 256
__global__ __launch_bounds__(512) void gh_kernel(
    const float* __restrict__ hs_t, float* __restrict__ hs_n,
    const bf16* __restrict__ hbf, bf16* __restrict__ hbf_n,
    const float* __restrict__ gi, const bf16* __restrict__ whhb,
    const float* __restrict__ b_ih, const float* __restrict__ b_hh,
    const int* __restrict__ act_mask, int t) {
  __shared__ bf16 Hs[64][BK + 8];
  __shared__ bf16 Wh[96][BK + 8];
  __shared__ int s_any;

  const int tid = threadIdx.x;
  const int c0 = blockIdx.x * 32;
  const int b0 = blockIdx.y * 64;

  if (tid == 0) s_any = 0;
  __syncthreads();
  if (tid < 64 && act_mask[(b0 + tid) * NT + t]) s_any = 1;  // benign race
  __syncthreads();

  if (!s_any) {  // whole tile inactive: pass h through (fp32 + bf16 copies)
    const int row = tid >> 3, c4 = (tid & 7) * 4;
    const size_t off = (size_t)(b0 + row) * NH + c0 + c4;
    const float4 v = *(const float4*)&hs_t[off];
    *(float4*)&hs_n[off] = v;
    union { bf16 h[4]; uint2 u; } p;
    p.h[0] = (bf16)v.x; p.h[1] = (bf16)v.y; p.h[2] = (bf16)v.z; p.h[3] = (bf16)v.w;
    *(uint2*)&hbf_n[off] = p.u;
    return;
  }

  const int wave = tid >> 6, lane = tid & 63;
  const int ln15 = lane & 15, q8 = (lane >> 4) * 8;
  const int wrow = (wave & 3) * 16;
  const int nt = wave >> 2;

  // epilogue operand prefetch (independent of the K-loop; hides tail latency)
  const int c = c0 + nt * 16 + ln15;
  const float bR = b_ih[c] + b_hh[c];
  const float bZ = b_ih[NH + c] + b_hh[NH + c];
  const float bI = b_ih[2 * NH + c];
  const float bH = b_hh[2 * NH + c];
  const int mbase = b0 + wrow + (lane >> 4) * 4;
  float giR[4], giZ[4], giN[4], hp[4];
  int actv[4];
#pragma unroll
  for (int i = 0; i < 4; ++i) {
    const int m = mbase + i;
    const size_t gr = ((size_t)m * NT + t) * NG;
    giR[i] = gi[gr + c];
    giZ[i] = gi[gr + NH + c];
    giN[i] = gi[gr + 2 * NH + c];
    hp[i]  = hs_t[(size_t)m * NH + c];
    actv[i] = act_mask[m * NT + t];
  }

  f32x4 aR = {0, 0, 0, 0}, aZ = {0, 0, 0, 0}, aN = {0, 0, 0, 0};

  for (int kb = 0; kb < NH; kb += BK) {
    if (kb) __syncthreads();
#pragma unroll
    for (int i = 0; i < 4; ++i) {  // stage Hs: 64 rows x 256 k (bf16)
      const int idx = tid + 512 * i;
      const int row = idx >> 5, c8 = (idx & 31) * 8;
      *(int4*)&Hs[row][c8] = *(const int4*)&hbf[(size_t)(b0 + row) * NH + kb + c8];
    }
#pragma unroll
    for (int i = 0; i < 6; ++i) {  // stage Wh: 96 rows x 256 k
      const int idx = tid + 512 * i;
      const int row = idx >> 5, c8 = (idx & 31) * 8;
      const int g = row >> 5, n = row & 31;
      *(int4*)&Wh[row][c8] = *(const int4*)&whhb[((size_t)g * NH + c0 + n) * NH + kb + c8];
    }
    __syncthreads();
#pragma unroll
    for (int k = 0; k < BK; k += 32) {
      const bf16x8 ah = *(const bf16x8*)&Hs[wrow + ln15][k + q8];
      const int wr = nt * 16 + ln15;
      const bf16x8 bhR = *(const bf16x8*)&Wh[wr][k + q8];
      const bf16x8 bhZ = *(const bf16x8*)&Wh[32 + wr][k + q8];
      const bf16x8 bhN = *(const bf16x8*)&Wh[64 + wr][k + q8];
      aR = __builtin_amdgcn_mfma_f32_16x16x32_bf16(ah, bhR, aR, 0, 0, 0);
      aZ = __builtin_amdgcn_mfma_f32_16x16x32_bf16(ah, bhZ, aZ, 0, 0, 0);
      aN = __builtin_amdgcn_mfma_f32_16x16x32_bf16(ah, bhN, aN, 0, 0, 0);
    }
  }

  // epilogue: C/D layout col=lane&15, row=(lane>>4)*4+reg
#pragma unroll
  for (int i = 0; i < 4; ++i) {
    const int m = mbase + i;
    const float r = sigmoid_f(aR[i] + giR[i] + bR);
    const float z = sigmoid_f(aZ[i] + giZ[i] + bZ);
    const float n = tanh_f(giN[i] + bI + r * (aN[i] + bH));
    const float o = actv[i] ? ((1.0f - z) * n + z * hp[i]) : hp[i];
    hs_n[(size_t)m * NH + c] = o;
    hbf_n[(size_t)m * NH + c] = (bf16)o;
  }
}

// ---------------- all LN emits in one pass: out[b][t] = LN(h_states[t][b]) --
__global__ void ln_all_kernel(const float* __restrict__ hs,  // [T][B][H]
                              const float* __restrict__ lnw,
                              const float* __restrict__ lnb,
                              float* __restrict__ out) {  // [B][T][H]
  const int r = blockIdx.x;  // t*NB + b
  const int t = r >> 10, b = r & (NB - 1);
  const int i = threadIdx.x * 2;
  const float2 hv = *(const float2*)&hs[(size_t)r * NH + i];
  float mean, rstd;
  ln_stats(hv.x + hv.y, hv.x * hv.x + hv.y * hv.y, mean, rstd);
  const float2 lw = *(const float2*)&lnw[i];
  const float2 lb = *(const float2*)&lnb[i];
  float2 o;
  o.x = (hv.x - mean) * rstd * lw.x + lb.x;
  o.y = (hv.y - mean) * rstd * lw.y + lb.y;
  *(float2*)&out[((size_t)b * NT + t) * NH + i] = o;
}

// ---------------- host-side launch ------------------------------------------
extern "C" void kernel_launch(void* const* d_in, const int* in_sizes, int n_in,
                              void* d_out, int out_size, void* d_ws, size_t ws_size,
                              hipStream_t stream) {
  const int*   actions      = (const int*)d_in[0];
  const float* edge_tokens  = (const float*)d_in[1];
  const int*   stop_indices = (const int*)d_in[2];
  const float* question     = (const float*)d_in[3];
  const float* node_tokens  = (const float*)d_in[4];
  const int*   start_locals = (const int*)d_in[5];
  const int*   start_ptr    = (const int*)d_in[6];
  const float* w_ih         = (const float*)d_in[7];
  const float* w_hh         = (const float*)d_in[8];
  const float* b_ih         = (const float*)d_in[9];
  const float* b_hh         = (const float*)d_in[10];
  const float* ln_w         = (const float*)d_in[11];
  const float* ln_b         = (const float*)d_in[12];
  float* out = (float*)d_out;

  // ws layout (~610 MB of ~1.5 GB)
  bf16* Wihbf = (bf16*)d_ws;
  bf16* Whhbf = Wihbf + (size_t)3 * NH * NH;
  bf16* Xbf   = Whhbf + (size_t)3 * NH * NH;
  float* GI   = (float*)(Xbf + (size_t)MALL * NH);        // [B*T][3H] fp32
  float* hstates = GI + (size_t)MALL * NG;                // [T][B][H] fp32
  bf16* Hb0 = (bf16*)(hstates + (size_t)NT * NB * NH);
  bf16* Hb1 = Hb0 + (size_t)NB * NH;
  int* act_mask = (int*)(Hb1 + (size_t)NB * NH);

  active_kernel<<<NB / 256, 256, 0, stream>>>(actions, stop_indices, act_mask);
  wcvt_kernel<<<(3 * NH * NH) / (256 * 4), 256, 0, stream>>>(w_ih, w_hh, Wihbf, Whhbf);
  xall_kernel<<<NB * NT, 256, 0, stream>>>(actions, edge_tokens, Xbf);
  h0_kernel<<<NB, 256, 0, stream>>>(question, node_tokens, start_locals, start_ptr,
                                    ln_w, ln_b, hstates, Hb0);

  // hoisted input-side GEMM: GI = X @ Wih^T  (103 GFLOP, one dispatch)
  gi_kernel<<<dim3(NG / 128, MALL / 128), 512, 0, stream>>>(Xbf, Wihbf, GI);

  bf16* hbc = Hb0;
  bf16* hbn = Hb1;
  for (int t = 0; t < NT - 1; ++t) {
    gh_kernel<<<dim3(NH / 32, NB / 64), 512, 0, stream>>>(
        hstates + (size_t)t * NB * NH, hstates + (size_t)(t + 1) * NB * NH,
        hbc, hbn, GI, Whhbf, b_ih, b_hh, act_mask, t);
    bf16* tmp = hbc; hbc = hbn; hbn = tmp;
  }

  ln_all_kernel<<<NB * NT, 256, 0, stream>>>(hstates, ln_w, ln_b, out);
}